// Round 1
// baseline (586.760 us; speedup 1.0000x reference)
//
#include <hip/hip_runtime.h>
#include <hip/hip_bf16.h>

// CGCNN: B=16, N=1024, M=12, F=64, BF=128, in_fea=256, 3 conv layers.
// Decomposition: total@cw = yself + gather(ynbr) + bond@cw3.  BN-a folded into cw/cb.

#define BB 16
#define NN 1024
#define MM 12
#define FF 64
#define BFE 128
#define S_BN 0.99950037f   // 1/sqrt(1+1e-3)

// ---- fold BN-a into core weights -------------------------------------------
__global__ void fold_w(const float* __restrict__ cw, const float* __restrict__ cb,
                       const float* __restrict__ g,  const float* __restrict__ bab,
                       float* __restrict__ cwp, float* __restrict__ cbp) {
    int i = blockIdx.x * 256 + threadIdx.x;           // 3*256*64
    if (i >= 3 * 256 * 64) return;
    int f = i & 63;
    int l = i / (256 * 64);
    float gs = g[l * 64 + f] * S_BN;
    cwp[i] = cw[i] * gs;
    if (((i >> 6) & 255) == 0)                        // k == 0
        cbp[l * 64 + f] = cb[l * 64 + f] * gs + bab[l * 64 + f];
}

// ---- embedding gather ------------------------------------------------------
__global__ void embed_k(const int* __restrict__ at, const float* __restrict__ emb,
                        float* __restrict__ x) {
    int i = blockIdx.x * 256 + threadIdx.x;           // B*N*F
    int f = i & 63;
    int bn = i >> 6;
    x[i] = emb[at[bn] * FF + f];
}

// ---- per-atom projections: yself(+cb'), ynbr, fself(+fb), fnbr -------------
__global__ __launch_bounds__(256) void atomproj(
    const float* __restrict__ x, const float* __restrict__ cwp_l,
    const float* __restrict__ cbp_l, const float* __restrict__ fw_l,
    const float* __restrict__ fb_l,
    float* __restrict__ ys, float* __restrict__ yn,
    float* __restrict__ fs, float* __restrict__ fn) {
    __shared__ float xs[4][64];
    int w = threadIdx.x >> 6, lane = threadIdx.x & 63;
    int row = blockIdx.x * 4 + w;                     // < B*N
    xs[w][lane] = x[row * 64 + lane];
    __syncthreads();
    float a1 = cbp_l[lane];
    float a2 = 0.f;
    float xl = xs[w][lane];
    float p1 = xl * fw_l[lane];
    float p2 = xl * fw_l[64 + lane];
    #pragma unroll 16
    for (int k = 0; k < 64; k++) {
        float xv = xs[w][k];
        a1 += xv * cwp_l[k * 64 + lane];
        a2 += xv * cwp_l[(64 + k) * 64 + lane];
    }
    ys[row * 64 + lane] = a1;
    yn[row * 64 + lane] = a2;
    #pragma unroll
    for (int off = 32; off; off >>= 1) {
        p1 += __shfl_xor(p1, off, 64);
        p2 += __shfl_xor(p2, off, 64);
    }
    if (lane == 0) { fs[row] = p1 + fb_l[0]; fn[row] = p2; }
}

// ---- main conv layer: bond matmul + filt + softmax + mean + BN-b + residual
__global__ __launch_bounds__(256) void cgcnn_main(
    const float* __restrict__ x,         // (B*N, 64)
    const float* __restrict__ bond,      // (B*N, 12, 128)
    const int*   __restrict__ nbr,       // (B*N, 12)
    const float* __restrict__ ys, const float* __restrict__ yn,
    const float* __restrict__ fs, const float* __restrict__ fn,
    const float* __restrict__ wb,        // folded cw' rows 128..255 : (128,64)
    const float* __restrict__ fwb,       // filt_w rows 128..255 : (128,)
    const float* __restrict__ bbg, const float* __restrict__ bbb,
    float* __restrict__ xout) {
    __shared__ float wsh[128 * 64];      // 32 KB
    __shared__ float bsh[4][MM * BFE];   // 24 KB (per-wave bond tile)
    __shared__ float fwsh[128];

    int tid = threadIdx.x;
    int w = tid >> 6, lane = tid & 63;
    int row = blockIdx.x * 4 + w;        // b*N + n
    int b = row >> 10;                   // N = 1024
    int base = b * NN;

    // stage weights (8192 floats -> 2048 float4)
    const float4* wsrc = (const float4*)wb;
    float4* wdst = (float4*)wsh;
    #pragma unroll
    for (int i = 0; i < 8; i++) wdst[tid + 256 * i] = wsrc[tid + 256 * i];
    if (tid < 128) fwsh[tid] = fwb[tid];

    // stage this wave's bond tile (1536 floats -> 384 float4)
    const float4* bsrc = (const float4*)(bond + (size_t)row * MM * BFE);
    float4* bdst = (float4*)(bsh[w]);
    #pragma unroll
    for (int i = 0; i < 6; i++) bdst[lane + 64 * i] = bsrc[lane + 64 * i];
    __syncthreads();

    // bond @ cw3 : lane = f, acc over all 12 m's (bond values are wave-broadcast)
    float acc[MM];
    #pragma unroll
    for (int m = 0; m < MM; m++) acc[m] = 0.f;
    #pragma unroll 4
    for (int k = 0; k < 128; k += 4) {
        float w0 = wsh[(k + 0) * 64 + lane];
        float w1 = wsh[(k + 1) * 64 + lane];
        float w2 = wsh[(k + 2) * 64 + lane];
        float w3 = wsh[(k + 3) * 64 + lane];
        #pragma unroll
        for (int m = 0; m < MM; m++) {
            float4 bv = *(const float4*)&bsh[w][m * BFE + k];
            acc[m] += bv.x * w0 + bv.y * w1 + bv.z * w2 + bv.w * w3;
        }
    }

    // filt bond part: lane-parallel dot, butterfly reduce (all lanes get sum)
    float fltv[MM];
    #pragma unroll
    for (int m = 0; m < MM; m++) {
        float p = bsh[w][m * BFE + lane] * fwsh[lane]
                + bsh[w][m * BFE + 64 + lane] * fwsh[64 + lane];
        #pragma unroll
        for (int off = 32; off; off >>= 1) p += __shfl_xor(p, off, 64);
        fltv[m] = p;
    }

    int jv[MM];
    #pragma unroll
    for (int m = 0; m < MM; m++) jv[m] = nbr[row * MM + m];

    float fsv = fs[row];
    float ysv = ys[row * 64 + lane];

    float fmax = -1e30f;
    #pragma unroll
    for (int m = 0; m < MM; m++) {
        fltv[m] += fsv + fn[base + jv[m]];
        fmax = fmaxf(fmax, fltv[m]);
    }
    float fsum = 0.f;
    #pragma unroll
    for (int m = 0; m < MM; m++) { fltv[m] = __expf(fltv[m] - fmax); fsum += fltv[m]; }
    float inv = 1.f / (12.f * fsum);

    float summed = 0.f;
    #pragma unroll
    for (int m = 0; m < MM; m++) {
        float core = acc[m] + ysv + yn[(size_t)(base + jv[m]) * 64 + lane];
        core = fmaxf(core, 0.f);                      // relu after folded BN-a
        summed += fltv[m] * core;
    }
    summed *= inv;

    float xv = x[row * 64 + lane];
    float o = xv + bbg[lane] * (summed * S_BN) + bbb[lane];
    xout[row * 64 + lane] = fmaxf(o, 0.f);
}

// ---- pooling gather + dense + relu ----------------------------------------
__global__ __launch_bounds__(256) void final_k(
    const float* __restrict__ x, const int* __restrict__ tidx,
    const float* __restrict__ dw, const float* __restrict__ db,
    float* __restrict__ out) {
    __shared__ float xs[4][64];
    __shared__ float wsh[64 * 64];       // 16 KB
    int tid = threadIdx.x;
    int w = tid >> 6, lane = tid & 63;
    const float4* src = (const float4*)dw;
    float4* dst = (float4*)wsh;
    #pragma unroll
    for (int i = 0; i < 4; i++) dst[tid + 256 * i] = src[tid + 256 * i];
    int row = blockIdx.x * 4 + w;        // b*64 + i
    int b = row >> 6;
    int t = tidx[row];
    float xv = x[((size_t)b * NN + t) * 64 + lane];
    xs[w][lane] = fmaxf(xv, 0.f);
    __syncthreads();
    float a = db[lane];
    #pragma unroll 16
    for (int k = 0; k < 64; k++) a += xs[w][k] * wsh[k * 64 + lane];
    out[row * 64 + lane] = fmaxf(a, 0.f);
}

extern "C" void kernel_launch(void* const* d_in, const int* in_sizes, int n_in,
                              void* d_out, int out_size, void* d_ws, size_t ws_size,
                              hipStream_t stream) {
    const int*   at   = (const int*)d_in[0];
    const float* bond = (const float*)d_in[1];
    const int*   nbr  = (const int*)d_in[2];
    const int*   tgt  = (const int*)d_in[3];
    const float* emb  = (const float*)d_in[4];
    const float* cw   = (const float*)d_in[5];
    const float* cb   = (const float*)d_in[6];
    const float* fw   = (const float*)d_in[7];
    const float* fb   = (const float*)d_in[8];
    const float* bag  = (const float*)d_in[9];
    const float* bab  = (const float*)d_in[10];
    const float* bbg  = (const float*)d_in[11];
    const float* bbb  = (const float*)d_in[12];
    const float* dw   = (const float*)d_in[13];
    const float* db   = (const float*)d_in[14];

    float* ws  = (float*)d_ws;
    float* xA  = ws;
    float* xB  = xA + (size_t)BB * NN * FF;
    float* cwp = xB + (size_t)BB * NN * FF;
    float* cbp = cwp + 3 * 256 * 64;
    float* ys  = cbp + 3 * 64;
    float* yn  = ys + (size_t)BB * NN * FF;
    float* fs  = yn + (size_t)BB * NN * FF;
    float* fn  = fs + (size_t)BB * NN;
    // total ~17 MB of workspace

    fold_w<<<(3 * 256 * 64 + 255) / 256, 256, 0, stream>>>(cw, cb, bag, bab, cwp, cbp);
    embed_k<<<(BB * NN * FF) / 256, 256, 0, stream>>>(at, emb, xA);

    float* xin = xA;
    float* xout = xB;
    for (int l = 0; l < 3; l++) {
        atomproj<<<BB * NN / 4, 256, 0, stream>>>(
            xin, cwp + (size_t)l * 256 * 64, cbp + l * 64, fw + l * 256, fb + l,
            ys, yn, fs, fn);
        cgcnn_main<<<BB * NN / 4, 256, 0, stream>>>(
            xin, bond, nbr, ys, yn, fs, fn,
            cwp + (size_t)l * 256 * 64 + 128 * 64, fw + l * 256 + 128,
            bbg + l * 64, bbb + l * 64, xout);
        float* t = xin; xin = xout; xout = t;
    }

    final_k<<<BB * 64 / 4, 256, 0, stream>>>(xin, tgt, dw, db, (float*)d_out);
}

// Round 2
// 290.117 us; speedup vs baseline: 2.0225x; 2.0225x over previous
//
#include <hip/hip_runtime.h>
#include <hip/hip_bf16.h>

// CGCNN: B=16, N=1024, M=12, F=64, BF=128, 3 conv layers.
// Key restructure: bond is layer-invariant, so core_l = bond @ cw3_l for ALL
// 3 layers (+ filt columns) is ONE bf16 MFMA GEMM reading bond once.
// Per-layer work = per-atom fp32 projections (atomproj) + light epilogue.

#define BB 16
#define NN 1024
#define MM 12
#define FF 64
#define BFE 128
#define RT (BB * NN * MM)   // 196608 bond rows
#define S_BN 0.99950037f    // 1/sqrt(1+1e-3)
#define WCOLS 208           // 192 core cols (3 layers x 64) + 3 filt + 13 pad
#define WSTR 136            // padded K stride (bf16 elems) -> conflict-free b128

typedef __attribute__((ext_vector_type(8))) short bf16x8;
typedef __attribute__((ext_vector_type(4))) float f32x4;

static __device__ __forceinline__ unsigned short f2bf(float f) {
    union { float f; unsigned u; } c; c.f = f;
    unsigned r = c.u + 0x7fff + ((c.u >> 16) & 1);   // RNE
    return (unsigned short)(r >> 16);
}
static __device__ __forceinline__ float bf2f(unsigned short s) {
    union { unsigned u; float f; } c; c.u = ((unsigned)s) << 16;
    return c.f;
}

// ---- fold BN-a into core weights (fp32 copy, used by atomproj rows 0..127) --
__global__ void fold_w(const float* __restrict__ cw, const float* __restrict__ cb,
                       const float* __restrict__ g,  const float* __restrict__ bab,
                       float* __restrict__ cwp, float* __restrict__ cbp) {
    int i = blockIdx.x * 256 + threadIdx.x;           // 3*256*64
    if (i >= 3 * 256 * 64) return;
    int f = i & 63;
    int l = i / (256 * 64);
    float gs = g[l * 64 + f] * S_BN;
    cwp[i] = cw[i] * gs;
    if (((i >> 6) & 255) == 0)
        cbp[l * 64 + f] = cb[l * 64 + f] * gs + bab[l * 64 + f];
}

// ---- build transposed bf16 weight panel wT[col][k] for the bond GEMM -------
// cols 0..191: layer l=col>>6, feature f=col&63, folded cw rows 128..255
// cols 192..194: filt_w rows 128..255 for layer col-192;  rest zero pad
__global__ void prep_wT(const float* __restrict__ cw, const float* __restrict__ g,
                        const float* __restrict__ fw, unsigned short* __restrict__ wT) {
    int i = blockIdx.x * 256 + threadIdx.x;           // WCOLS*WSTR = 28288
    if (i >= WCOLS * WSTR) return;
    int col = i / WSTR, k = i % WSTR;
    float v = 0.f;
    if (k < 128) {
        if (col < 192) {
            int l = col >> 6, f = col & 63;
            v = cw[(l * 256 + 128 + k) * 64 + f] * g[l * 64 + f] * S_BN;
        } else if (col < 195) {
            int l = col - 192;
            v = fw[l * 256 + 128 + k];
        }
    }
    wT[i] = f2bf(v);
}

// ---- embedding gather ------------------------------------------------------
__global__ void embed_k(const int* __restrict__ at, const float* __restrict__ emb,
                        float* __restrict__ x) {
    int i = blockIdx.x * 256 + threadIdx.x;
    int f = i & 63;
    int bn = i >> 6;
    x[i] = emb[at[bn] * FF + f];
}

// ---- one-shot bf16 MFMA GEMM: core_{0,1,2} (bf16) + filt_{0,1,2} (fp32) ----
// A = bond (196608 x 128, fp32 -> bf16 inline), B = wT (128 x 208)
__global__ __launch_bounds__(256) void gemm_bond(
    const float* __restrict__ bond, const unsigned short* __restrict__ wT,
    unsigned short* __restrict__ core, float* __restrict__ filt) {
    __shared__ unsigned short bsh[WCOLS * WSTR];  // 56576 B weights
    __shared__ unsigned short ash[64 * WSTR];     // 17408 B A-tile
    int tid = threadIdx.x;
    int w = tid >> 6, lane = tid & 63;
    int row0 = blockIdx.x * 64;

    // stage weights (3536 float4)
    const float4* wsrc = (const float4*)wT;
    float4* wdst = (float4*)bsh;
    #pragma unroll
    for (int i = 0; i < 14; i++) {
        int idx = tid + 256 * i;
        if (idx < (WCOLS * WSTR * 2) / 16) wdst[idx] = wsrc[idx];
    }
    // stage A tile: 64 rows x 128 k fp32, convert to bf16 (2048 float4)
    const float4* bsrc = (const float4*)(bond + (size_t)row0 * BFE);
    #pragma unroll
    for (int i = 0; i < 8; i++) {
        int idx = tid + 256 * i;
        float4 v = bsrc[idx];
        int r = idx >> 5, c4 = idx & 31;
        ushort4 h;
        h.x = f2bf(v.x); h.y = f2bf(v.y); h.z = f2bf(v.z); h.w = f2bf(v.w);
        *(ushort4*)&ash[r * WSTR + c4 * 4] = h;
    }
    __syncthreads();

    int m = lane & 15, quad = lane >> 4;
    f32x4 acc[13];
    #pragma unroll
    for (int t = 0; t < 13; t++) acc[t] = (f32x4){0.f, 0.f, 0.f, 0.f};

    #pragma unroll
    for (int c = 0; c < 4; c++) {
        bf16x8 af = *(const bf16x8*)&ash[(w * 16 + m) * WSTR + c * 32 + quad * 8];
        #pragma unroll
        for (int t = 0; t < 13; t++) {
            bf16x8 bfv = *(const bf16x8*)&bsh[(t * 16 + m) * WSTR + c * 32 + quad * 8];
            acc[t] = __builtin_amdgcn_mfma_f32_16x16x32_bf16(af, bfv, acc[t], 0, 0, 0);
        }
    }

    // epilogue: C row = quad*4+r, col = lane&15 (m89-verified layout)
    int rbase = row0 + w * 16 + quad * 4;
    #pragma unroll
    for (int t = 0; t < 12; t++) {
        int l = t >> 2;
        int f = (t & 3) * 16 + m;
        #pragma unroll
        for (int r = 0; r < 4; r++)
            core[((size_t)l * RT + rbase + r) * 64 + f] = f2bf(acc[t][r]);
    }
    if (m < 3) {
        #pragma unroll
        for (int r = 0; r < 4; r++)
            filt[(size_t)m * RT + rbase + r] = acc[12][r];
    }
}

// ---- per-atom projections (persistent LDS weights) -------------------------
__global__ __launch_bounds__(256) void atomproj(
    const float* __restrict__ x, const float* __restrict__ cwp_l,
    const float* __restrict__ cbp_l, const float* __restrict__ fw_l,
    const float* __restrict__ fb_l,
    float* __restrict__ ys, float* __restrict__ yn,
    float* __restrict__ fs, float* __restrict__ fn) {
    __shared__ float wsh[128 * 64];   // 32 KB: folded cw rows 0..127
    __shared__ float xs[4][64];
    int tid = threadIdx.x, w = tid >> 6, lane = tid & 63;
    #pragma unroll
    for (int i = 0; i < 8; i++)
        ((float4*)wsh)[tid + 256 * i] = ((const float4*)cwp_l)[tid + 256 * i];
    float fw1 = fw_l[lane], fw2 = fw_l[64 + lane];
    float cb = cbp_l[lane], fbv = fb_l[0];
    __syncthreads();
    #pragma unroll 1
    for (int it = 0; it < 4; it++) {
        int row = (blockIdx.x * 4 + it) * 4 + w;      // grid 1024 -> 16384 rows
        float xl = x[(size_t)row * 64 + lane];
        xs[w][lane] = xl;                              // wave-private tile
        float a1 = cb, a2 = 0.f;
        #pragma unroll 16
        for (int k = 0; k < 64; k++) {
            float xv = xs[w][k];
            a1 += xv * wsh[k * 64 + lane];
            a2 += xv * wsh[(64 + k) * 64 + lane];
        }
        ys[(size_t)row * 64 + lane] = a1;
        yn[(size_t)row * 64 + lane] = a2;
        float p1 = xl * fw1, p2 = xl * fw2;
        #pragma unroll
        for (int off = 32; off; off >>= 1) {
            p1 += __shfl_xor(p1, off, 64);
            p2 += __shfl_xor(p2, off, 64);
        }
        if (lane == 0) { fs[row] = p1 + fbv; fn[row] = p2; }
    }
}

// ---- per-layer epilogue: softmax + weighted mean + BN-b + residual ---------
__global__ __launch_bounds__(256) void layer_ep(
    const float* __restrict__ x, const unsigned short* __restrict__ core_l,
    const float* __restrict__ filt_l, const int* __restrict__ nbr,
    const float* __restrict__ ys, const float* __restrict__ yn,
    const float* __restrict__ fs, const float* __restrict__ fn,
    const float* __restrict__ bbg, const float* __restrict__ bbb,
    float* __restrict__ xout) {
    int tid = threadIdx.x, w = tid >> 6, lane = tid & 63;
    int row = blockIdx.x * 4 + w;
    int base = (row >> 10) * NN;
    size_t rb = (size_t)row * MM;

    int jv[MM]; float fltv[MM], corev[MM];
    #pragma unroll
    for (int mm = 0; mm < MM; mm++) jv[mm] = nbr[rb + mm];
    float fsv = fs[row], ysv = ys[(size_t)row * 64 + lane];
    #pragma unroll
    for (int mm = 0; mm < MM; mm++)
        fltv[mm] = filt_l[rb + mm] + fsv + fn[base + jv[mm]];
    #pragma unroll
    for (int mm = 0; mm < MM; mm++)
        corev[mm] = bf2f(core_l[(rb + mm) * 64 + lane]) + ysv
                  + yn[(size_t)(base + jv[mm]) * 64 + lane];
    float fmax = -1e30f;
    #pragma unroll
    for (int mm = 0; mm < MM; mm++) fmax = fmaxf(fmax, fltv[mm]);
    float fsum = 0.f;
    #pragma unroll
    for (int mm = 0; mm < MM; mm++) { fltv[mm] = __expf(fltv[mm] - fmax); fsum += fltv[mm]; }
    float inv = 1.f / (12.f * fsum);
    float summed = 0.f;
    #pragma unroll
    for (int mm = 0; mm < MM; mm++) summed += fltv[mm] * fmaxf(corev[mm], 0.f);
    summed *= inv;
    float o = x[(size_t)row * 64 + lane] + bbg[lane] * (summed * S_BN) + bbb[lane];
    xout[(size_t)row * 64 + lane] = fmaxf(o, 0.f);
}

// ---- pooling gather + dense + relu ----------------------------------------
__global__ __launch_bounds__(256) void final_k(
    const float* __restrict__ x, const int* __restrict__ tidx,
    const float* __restrict__ dw, const float* __restrict__ db,
    float* __restrict__ out) {
    __shared__ float xs[4][64];
    __shared__ float wsh[64 * 64];
    int tid = threadIdx.x;
    int w = tid >> 6, lane = tid & 63;
    const float4* src = (const float4*)dw;
    float4* dst = (float4*)wsh;
    #pragma unroll
    for (int i = 0; i < 4; i++) dst[tid + 256 * i] = src[tid + 256 * i];
    int row = blockIdx.x * 4 + w;        // b*64 + i
    int b = row >> 6;
    int t = tidx[row];
    float xv = x[((size_t)b * NN + t) * 64 + lane];
    xs[w][lane] = fmaxf(xv, 0.f);
    __syncthreads();
    float a = db[lane];
    #pragma unroll 16
    for (int k = 0; k < 64; k++) a += xs[w][k] * wsh[k * 64 + lane];
    out[row * 64 + lane] = fmaxf(a, 0.f);
}

extern "C" void kernel_launch(void* const* d_in, const int* in_sizes, int n_in,
                              void* d_out, int out_size, void* d_ws, size_t ws_size,
                              hipStream_t stream) {
    const int*   at   = (const int*)d_in[0];
    const float* bond = (const float*)d_in[1];
    const int*   nbr  = (const int*)d_in[2];
    const int*   tgt  = (const int*)d_in[3];
    const float* emb  = (const float*)d_in[4];
    const float* cw   = (const float*)d_in[5];
    const float* cb   = (const float*)d_in[6];
    const float* fw   = (const float*)d_in[7];
    const float* fb   = (const float*)d_in[8];
    const float* bag  = (const float*)d_in[9];
    const float* bab  = (const float*)d_in[10];
    const float* bbg  = (const float*)d_in[11];
    const float* bbb  = (const float*)d_in[12];
    const float* dw   = (const float*)d_in[13];
    const float* db   = (const float*)d_in[14];

    float* ws   = (float*)d_ws;
    float* xA   = ws;
    float* xB   = xA + (size_t)BB * NN * FF;          // 1,048,576 each
    float* cwp  = xB + (size_t)BB * NN * FF;          // 49,152
    float* cbp  = cwp + 3 * 256 * 64;                 // 192
    float* ys   = cbp + 192;                          // 1,048,576
    float* yn   = ys + (size_t)BB * NN * FF;          // 1,048,576
    float* fs   = yn + (size_t)BB * NN * FF;          // 16,384
    float* fn   = fs + (size_t)BB * NN;               // 16,384
    float* filt = fn + (size_t)BB * NN;               // 3*196608 fp32
    unsigned short* wT   = (unsigned short*)(filt + 3 * (size_t)RT);  // 28,288 bf16
    unsigned short* core = wT + WCOLS * WSTR;         // 3*196608*64 bf16 (~75.5 MB)
    // total ~95 MB

    fold_w<<<(3 * 256 * 64 + 255) / 256, 256, 0, stream>>>(cw, cb, bag, bab, cwp, cbp);
    prep_wT<<<(WCOLS * WSTR + 255) / 256, 256, 0, stream>>>(cw, bag, fw, wT);
    embed_k<<<(BB * NN * FF) / 256, 256, 0, stream>>>(at, emb, xA);
    gemm_bond<<<RT / 64, 256, 0, stream>>>(bond, wT, core, filt);

    float* xin = xA;
    float* xout = xB;
    for (int l = 0; l < 3; l++) {
        atomproj<<<BB * NN / 16, 256, 0, stream>>>(
            xin, cwp + (size_t)l * 256 * 64, cbp + l * 64, fw + l * 256, fb + l,
            ys, yn, fs, fn);
        layer_ep<<<BB * NN / 4, 256, 0, stream>>>(
            xin, core + (size_t)l * RT * 64, filt + (size_t)l * RT, nbr,
            ys, yn, fs, fn, bbg + l * 64, bbb + l * 64, xout);
        float* t = xin; xin = xout; xout = t;
    }

    final_k<<<BB * 64 / 4, 256, 0, stream>>>(xin, tgt, dw, db, (float*)d_out);
}